// Round 9
// baseline (262.182 us; speedup 1.0000x reference)
//
#include <hip/hip_runtime.h>
#include <hip/hip_bf16.h>
#include <math.h>

#define S_LEN 2048
#define HID   2048
#define NH    32
#define NKV   8
#define HD    64
#define QKD   2560   // QK buffer row stride: Q[0:2048] | K[2048:2560]
#define LOG2E 1.44269504f
#define L2THETA_32 0.591611505f   // log2(500000)/32

typedef unsigned short u16;
typedef __attribute__((ext_vector_type(8))) short short8;   // 8 bf16 (MFMA A/B frag)
typedef __attribute__((ext_vector_type(4))) float f32x4;    // MFMA C/D frag

__device__ __forceinline__ u16 f2bf(float x) {
    union { __hip_bfloat16 b; u16 u; } c; c.b = __float2bfloat16(x); return c.u;
}
__device__ __forceinline__ float bf2f(u16 u) {
    union { unsigned int i; float f; } c; c.i = ((unsigned int)u) << 16; return c.f;
}
__device__ __forceinline__ void async_copy16(void* lds, const void* g) {
    __builtin_amdgcn_global_load_lds((const __attribute__((address_space(1))) unsigned int*)g,
                                     (__attribute__((address_space(3))) unsigned int*)lds,
                                     16, 0, 0);
}

// ---------------------------------------------------------------------------
__global__ __launch_bounds__(256)
void cast_bf16(const float* __restrict__ in, u16* __restrict__ out, int n8) {
    int i = blockIdx.x * blockDim.x + threadIdx.x;
    if (i >= n8) return;
    const float4* p = (const float4*)(in + (size_t)i * 8);
    float4 a = p[0], b = p[1];
    short8 o;
    o[0] = f2bf(a.x); o[1] = f2bf(a.y); o[2] = f2bf(a.z); o[3] = f2bf(a.w);
    o[4] = f2bf(b.x); o[5] = f2bf(b.y); o[6] = f2bf(b.z); o[7] = f2bf(b.w);
    *(short8*)(out + (size_t)i * 8) = o;
}

// ---------------------------------------------------------------------------
// All four weight transposes in one dispatch. z selects the weight.
// ---------------------------------------------------------------------------
__global__ __launch_bounds__(256)
void transpose_all(const float* __restrict__ Wq, const float* __restrict__ Wk,
                   const float* __restrict__ Wv, const float* __restrict__ Wo,
                   u16* __restrict__ WqkvT, u16* __restrict__ WoT) {
    const float* W; u16* WT; int Nin, xT;
    switch (blockIdx.z) {
        case 0:  W = Wq; WT = WqkvT;                         Nin = 2048; xT = 64; break;
        case 1:  W = Wk; WT = WqkvT + (size_t)2048 * 2048;   Nin = 512;  xT = 16; break;
        case 2:  W = Wv; WT = WqkvT + (size_t)2560 * 2048;   Nin = 512;  xT = 16; break;
        default: W = Wo; WT = WoT;                           Nin = 2048; xT = 64; break;
    }
    if ((int)blockIdx.x >= xT) return;
    __shared__ float tile[32][33];
    const int tx = threadIdx.x & 31, ty = threadIdx.x >> 5;
    const int x = blockIdx.x * 32 + tx;
#pragma unroll
    for (int j = ty; j < 32; j += 8)
        tile[j][tx] = W[(size_t)(blockIdx.y * 32 + j) * Nin + x];
    __syncthreads();
    const int xo = blockIdx.y * 32 + tx;
#pragma unroll
    for (int j = ty; j < 32; j += 8)
        WT[(size_t)(blockIdx.x * 32 + j) * 2048 + xo] = f2bf(tile[tx][j]);
}

// ---------------------------------------------------------------------------
// Standalone RoPE over Q (hh 0..31) and K (hh 32..39). Q gets 0.125*log2e
// folded in (attention works in the log2 domain and calls exp2 directly).
// ---------------------------------------------------------------------------
__global__ __launch_bounds__(256)
void rope_qk(u16* __restrict__ QK, const int* __restrict__ pos) {
    int idx = blockIdx.x * blockDim.x + threadIdx.x;
    int d = idx & 31;
    int hh = (idx >> 5) % 40;
    int s = idx / (32 * 40);
    if (s >= S_LEN) return;
    float p = (float)pos[s];
    float inv_freq = exp2f(-(float)d * L2THETA_32);   // theta^(-d/32)
    float ang = p * inv_freq;
    float c = cosf(ang), sn = sinf(ang);
    float sc = (hh < 32) ? 0.125f * LOG2E : 1.0f;
    u16* b = QK + (size_t)s * QKD + hh * HD;
    float x0 = bf2f(b[d]), x1 = bf2f(b[d + 32]);
    b[d]      = f2bf((x0 * c - x1 * sn) * sc);
    b[d + 32] = f2bf((x1 * c + x0 * sn) * sc);
}

// ---------------------------------------------------------------------------
// bf16 GEMM, K-loop TRIPLE-buffered (R8): C = A[M,K] @ Bt[N,K]^T. 128x128
// tile, BK=32, 3 LDS buffers; 2 k-tiles (8 vm ops) stay in flight across the
// acquire barrier (s_waitcnt vmcnt(8)) — covers ~2 iterations (~700-1000 cyc)
// of load latency, matching cold-HBM global_load_lds (~900 cyc), needed
// because these grids run at ~1 block/CU (no cross-block hiding).
// MODE 0: fp32 C (stride N).
// MODE 1: QKV epilogue — cols <2560 -> bf16 QK (stride QKD); cols >=2560 ->
// V written TRANSPOSED to Vt[d][s].
// ---------------------------------------------------------------------------
template<int MODE>
__global__ __launch_bounds__(256)
void gemm_bt(const u16* __restrict__ A, const u16* __restrict__ Bt,
             void* __restrict__ Cv, u16* __restrict__ Vt, int M, int N, int K) {
    __shared__ __attribute__((aligned(16))) u16 As[3][4096];   // 3 x 8KB
    __shared__ __attribute__((aligned(16))) u16 Bs[3][4096];   // 3 x 8KB
    const int t = threadIdx.x;
    const int lane = t & 63;
    const int w = t >> 6;
    const int lm = lane & 15, quad = lane >> 4;
    const int row0 = blockIdx.y * 128, col0 = blockIdx.x * 128;
    const int wr = (w >> 1) * 64, wc = (w & 1) * 64;

    f32x4 acc[4][4];
#pragma unroll
    for (int i = 0; i < 4; ++i)
#pragma unroll
        for (int j = 0; j < 4; ++j) acc[i][j] = (f32x4){0.f, 0.f, 0.f, 0.f};

    const size_t strideB = (size_t)K * 2;
    const char* Ab = (const char*)(A + (size_t)row0 * K);
    const char* Bb = (const char*)(Bt + (size_t)col0 * K);

    // stage one 128x32 k-tile pair: exactly 4 vm ops
    auto stage = [&](int k0, int buf) {
#pragma unroll
        for (int i = 0; i < 2; ++i) {
            const int f = i * 4096 + t * 16;
            const int r = f >> 6, cb = f & 63;
            async_copy16((char*)As[buf] + f, Ab + (size_t)r * strideB + k0 * 2 + cb);
            async_copy16((char*)Bs[buf] + f, Bb + (size_t)r * strideB + k0 * 2 + cb);
        }
    };

    const int nk = K >> 5;
    stage(0, 0);
    if (nk > 1) stage(32, 1);
    if (nk > 2) stage(64, 2);

    int cur = 0;
    for (int kk = 0; kk < nk; ++kk) {
        // acquire: tile kk resident; up to 2 later tiles (8 ops) in flight
        if (kk + 2 < nk)      { asm volatile("s_waitcnt vmcnt(8)\ns_barrier" ::: "memory"); }
        else if (kk + 1 < nk) { asm volatile("s_waitcnt vmcnt(4)\ns_barrier" ::: "memory"); }
        else                  { asm volatile("s_waitcnt vmcnt(0)\ns_barrier" ::: "memory"); }

        short8 af[4], bfv[4];
#pragma unroll
        for (int i = 0; i < 4; ++i)
            af[i] = *(const short8*)((const char*)As[cur] + (wr + 16 * i + lm) * 64 + quad * 16);
#pragma unroll
        for (int j = 0; j < 4; ++j)
            bfv[j] = *(const short8*)((const char*)Bs[cur] + (wc + 16 * j + lm) * 64 + quad * 16);
#pragma unroll
        for (int i = 0; i < 4; ++i)
#pragma unroll
            for (int j = 0; j < 4; ++j)
                acc[i][j] = __builtin_amdgcn_mfma_f32_16x16x32_bf16(af[i], bfv[j], acc[i][j], 0, 0, 0);

        // release: frag reads drained -> safe to re-stage this buffer
        asm volatile("s_waitcnt lgkmcnt(0)\ns_barrier" ::: "memory");
        if (kk + 3 < nk) stage((kk + 3) * 32, cur);
        cur = (cur == 2) ? 0 : cur + 1;
    }

    // C/D layout: col = lane&15, row = quad*4 + reg  [m89-verified]
    const int cr = quad * 4;
#pragma unroll
    for (int i = 0; i < 4; ++i) {
        const int gr = row0 + wr + 16 * i + cr;
#pragma unroll
        for (int j = 0; j < 4; ++j) {
            const int gc = col0 + wc + 16 * j + lm;
            if (MODE == 0) {
#pragma unroll
                for (int rr = 0; rr < 4; ++rr)
                    ((float*)Cv)[(size_t)(gr + rr) * N + gc] = acc[i][j][rr];
            } else if (gc < 2560) {
#pragma unroll
                for (int rr = 0; rr < 4; ++rr)
                    ((u16*)Cv)[(size_t)(gr + rr) * QKD + gc] = f2bf(acc[i][j][rr]);
            } else {
                const int d = gc - 2560;
                ushort4 vv;
                vv.x = f2bf(acc[i][j][0]); vv.y = f2bf(acc[i][j][1]);
                vv.z = f2bf(acc[i][j][2]); vv.w = f2bf(acc[i][j][3]);
                *(ushort4*)(Vt + (size_t)d * S_LEN + gr) = vv;
            }
        }
    }
}

// ---------------------------------------------------------------------------
// MFMA flash attention, Q-tile 128 (unchanged from R7 — 58.9 us). grid=
// (16 qtiles, 32 heads), 256 thr / 4 waves; wave w owns TWO 16-row q-groups
// (independent MFMA chains, shared K/V frags). KV-64 double-buffered with
// prefetch-in-flight (vmcnt(4) acquire). Q staging LDS aliased by P buffer.
// Scores in log2 domain, fixed cap -16; row sums via ones-fragment MFMA.
// ---------------------------------------------------------------------------
__global__ __launch_bounds__(256)
void attn_mfma(const u16* __restrict__ QK, const u16* __restrict__ Vtg,
               u16* __restrict__ Ctx) {
    // union region: Q staging (2 slabs x 8192B) then P (128 x 144B = 18432B)
    __shared__ __attribute__((aligned(16))) u16 QPs[9216];       // 18432B
    __shared__ __attribute__((aligned(16))) u16 Ks[2][4096];     // 2 x 8KB
    __shared__ __attribute__((aligned(16))) u16 Vts[2][4096];    // 2 x 8KB

    const int t = threadIdx.x;
    const int lane = t & 63;
    const int w = t >> 6;
    const int lm = lane & 15, quad = lane >> 4;
    const int qt = (gridDim.x - 1) - blockIdx.x;   // longest first (LPT)
    const int h = blockIdx.y;
    const int kh = h >> 2;
    const int q0 = qt * 128;
    const int njt = 2 * qt + 2;                    // kv tiles of 64

    const char* Kb = (const char*)(QK + 2048 + kh * HD);
    const char* Vb = (const char*)(Vtg + (size_t)(kh * 64) * S_LEN);

    const int rr4 = t >> 2, cb4 = (t & 3) * 16;

    // stage Q: wave w stages rows [w*32, w*32+32) for both k-slabs (4 vm ops;
    // read-set == staged-set per wave -> per-wave vmcnt wait is sufficient)
    {
        const char* qb = (const char*)(QK + h * HD);
#pragma unroll
        for (int i = 0; i < 2; ++i)
#pragma unroll
            for (int j = 0; j < 2; ++j)
                async_copy16((char*)QPs + i * 8192 + w * 2048 + j * 1024 + lane * 16,
                             qb + (size_t)(q0 + w * 32 + j * 16 + (lane >> 2)) * (QKD * 2)
                                + i * 64 + (lane & 3) * 16);
    }

    auto stage_kv = [&](int jt_, int buf) {
        const int j0_ = jt_ * 64;
        const char* kp = Kb + (size_t)(j0_ + rr4) * (QKD * 2) + cb4;
        const char* vp = Vb + (size_t)rr4 * (S_LEN * 2) + j0_ * 2 + cb4;
        char* kl = (char*)Ks + buf * 8192 + t * 16;
        char* vl = (char*)Vts + buf * 8192 + t * 16;
        async_copy16(kl, kp);
        async_copy16(kl + 4096, kp + 64);
        async_copy16(vl, vp);
        async_copy16(vl + 4096, vp + 64);
    };

    stage_kv(0, 0);
    stage_kv(1, 1);   // njt >= 2 always

    // wait for this wave's Q (4 oldest of 12); KV prefetches stay in flight
    asm volatile("s_waitcnt vmcnt(8)" ::: "memory");

    // one-time Q fragment loads (B-operand: rows = q)
    const int ra = w * 32 + lm, rb = ra + 16;
    const short8 qa0 = *(const short8*)((const char*)QPs +        ra * 64 + quad * 16);
    const short8 qa1 = *(const short8*)((const char*)QPs + 8192 + ra * 64 + quad * 16);
    const short8 qb0 = *(const short8*)((const char*)QPs +        rb * 64 + quad * 16);
    const short8 qb1 = *(const short8*)((const char*)QPs + 8192 + rb * 64 + quad * 16);
    // drain Q reads before any wave can alias QPs with P writes
    asm volatile("s_waitcnt lgkmcnt(0)" ::: "memory");

    // constant ones A-frag: row m=0 (lanes with lm==0) = 1.0
    short8 onesf;
    {
        const short ob = (lm == 0) ? (short)0x3F80 : (short)0;
#pragma unroll
        for (int j = 0; j < 8; ++j) onesf[j] = ob;
    }

    f32x4 oa[4], ob_[4], la, lb;
#pragma unroll
    for (int dt = 0; dt < 4; ++dt) { oa[dt] = (f32x4){0.f,0.f,0.f,0.f}; ob_[dt] = (f32x4){0.f,0.f,0.f,0.f}; }
    la = (f32x4){0.f, 0.f, 0.f, 0.f};
    lb = (f32x4){0.f, 0.f, 0.f, 0.f};

    const int ql_a = ra, ql_b = rb;   // local q row of this lane per group

    for (int jt = 0; jt < njt; ++jt) {
        const int cur = jt & 1;
        if (jt + 1 < njt) { asm volatile("s_waitcnt vmcnt(4)\ns_barrier" ::: "memory"); }
        else              { asm volatile("s_waitcnt vmcnt(0)\ns_barrier" ::: "memory"); }

        const char* Kc = (const char*)Ks + cur * 8192;
        const char* Vc = (const char*)Vts + cur * 8192;

        // S^T = K Q^T for both q-groups (shared K frags), log2 domain, cap -16
        f32x4 sa[4], sb[4];
#pragma unroll
        for (int ct = 0; ct < 4; ++ct) {
            sa[ct] = (f32x4){-16.f, -16.f, -16.f, -16.f};
            sb[ct] = (f32x4){-16.f, -16.f, -16.f, -16.f};
        }
#pragma unroll
        for (int ct = 0; ct < 4; ++ct) {
            short8 kf0 = *(const short8*)(Kc + (ct * 16 + lm) * 64 + quad * 16);
            short8 kf1 = *(const short8*)(Kc + 4096 + (ct * 16 + lm) * 64 + quad * 16);
            sa[ct] = __builtin_amdgcn_mfma_f32_16x16x32_bf16(kf0, qa0, sa[ct], 0, 0, 0);
            sa[ct] = __builtin_amdgcn_mfma_f32_16x16x32_bf16(kf1, qa1, sa[ct], 0, 0, 0);
            sb[ct] = __builtin_amdgcn_mfma_f32_16x16x32_bf16(kf0, qb0, sb[ct], 0, 0, 0);
            sb[ct] = __builtin_amdgcn_mfma_f32_16x16x32_bf16(kf1, qb1, sb[ct], 0, 0, 0);
        }
        // causal mask on the two diagonal-overlapping tiles
        if (jt >= 2 * qt) {
            const int off = (jt - 2 * qt) * 64;
#pragma unroll
            for (int ct = 0; ct < 4; ++ct) {
                const int kvl = off + ct * 16 + quad * 4;
#pragma unroll
                for (int r = 0; r < 4; ++r) {
                    if (kvl + r > ql_a) sa[ct][r] = -1e30f;
                    if (kvl + r > ql_b) sb[ct][r] = -1e30f;
                }
            }
        }
        // p = exp2(s); pack 4 kv -> one b64 LDS write per ct per group
#pragma unroll
        for (int ct = 0; ct < 4; ++ct) {
            ushort4 pka, pkb;
            pka.x = f2bf(__builtin_amdgcn_exp2f(sa[ct][0]));
            pka.y = f2bf(__builtin_amdgcn_exp2f(sa[ct][1]));
            pka.z = f2bf(__builtin_amdgcn_exp2f(sa[ct][2]));
            pka.w = f2bf(__builtin_amdgcn_exp2f(sa[ct][3]));
            pkb.x = f2bf(__builtin_amdgcn_exp2f(sb[ct][0]));
            pkb.y = f2bf(__builtin_amdgcn_exp2f(sb[ct][1]));
            pkb.z = f2bf(__builtin_amdgcn_exp2f(sb[ct][2]));
            pkb.w = f2bf(__builtin_amdgcn_exp2f(sb[ct][3]));
            *(ushort4*)((char*)QPs + ra * 144 + ct * 32 + quad * 8) = pka;
            *(ushort4*)((char*)QPs + rb * 144 + ct * 32 + quad * 8) = pkb;
        }
        // P frags (wave-private rows, in-order LDS pipe)
        const short8 pa0 = *(const short8*)((const char*)QPs + ra * 144 +      quad * 16);
        const short8 pa1 = *(const short8*)((const char*)QPs + ra * 144 + 64 + quad * 16);
        const short8 pb0 = *(const short8*)((const char*)QPs + rb * 144 +      quad * 16);
        const short8 pb1 = *(const short8*)((const char*)QPs + rb * 144 + 64 + quad * 16);
        // O^T += V^T P^T for both groups (shared V frags); l += ones . P
#pragma unroll
        for (int dt = 0; dt < 4; ++dt) {
            short8 vf0 = *(const short8*)(Vc + (dt * 16 + lm) * 64 + quad * 16);
            short8 vf1 = *(const short8*)(Vc + 4096 + (dt * 16 + lm) * 64 + quad * 16);
            oa[dt]  = __builtin_amdgcn_mfma_f32_16x16x32_bf16(vf0, pa0, oa[dt], 0, 0, 0);
            oa[dt]  = __builtin_amdgcn_mfma_f32_16x16x32_bf16(vf1, pa1, oa[dt], 0, 0, 0);
            ob_[dt] = __builtin_amdgcn_mfma_f32_16x16x32_bf16(vf0, pb0, ob_[dt], 0, 0, 0);
            ob_[dt] = __builtin_amdgcn_mfma_f32_16x16x32_bf16(vf1, pb1, ob_[dt], 0, 0, 0);
        }
        la = __builtin_amdgcn_mfma_f32_16x16x32_bf16(onesf, pa0, la, 0, 0, 0);
        la = __builtin_amdgcn_mfma_f32_16x16x32_bf16(onesf, pa1, la, 0, 0, 0);
        lb = __builtin_amdgcn_mfma_f32_16x16x32_bf16(onesf, pb0, lb, 0, 0, 0);
        lb = __builtin_amdgcn_mfma_f32_16x16x32_bf16(onesf, pb1, lb, 0, 0, 0);

        // all waves done reading buf[cur] -> safe to prefetch jt+2 into it
        asm volatile("s_waitcnt lgkmcnt(0)\ns_barrier" ::: "memory");
        if (jt + 2 < njt) stage_kv(jt + 2, cur);
    }

    // l for q-row ra/rb lives in lane lm (quad 0), reg 0 -> broadcast
    const float inva = 1.f / __shfl(la[0], lm);
    const float invb = 1.f / __shfl(lb[0], lm);
    const int rowa = q0 + ra, rowb = q0 + rb;
#pragma unroll
    for (int dt = 0; dt < 4; ++dt) {
        ushort4 o;
        o.x = f2bf(oa[dt][0] * inva); o.y = f2bf(oa[dt][1] * inva);
        o.z = f2bf(oa[dt][2] * inva); o.w = f2bf(oa[dt][3] * inva);
        *(ushort4*)(Ctx + (size_t)rowa * HID + h * HD + dt * 16 + quad * 4) = o;
        ushort4 p;
        p.x = f2bf(ob_[dt][0] * invb); p.y = f2bf(ob_[dt][1] * invb);
        p.z = f2bf(ob_[dt][2] * invb); p.w = f2bf(ob_[dt][3] * invb);
        *(ushort4*)(Ctx + (size_t)rowb * HID + h * HD + dt * 16 + quad * 4) = p;
    }
}

// ---------------------------------------------------------------------------
extern "C" void kernel_launch(void* const* d_in, const int* in_sizes, int n_in,
                              void* d_out, int out_size, void* d_ws, size_t ws_size,
                              hipStream_t stream) {
    const float* X   = (const float*)d_in[0];
    const int*   pos = (const int*)d_in[1];
    const float* Wq  = (const float*)d_in[2];
    const float* Wk  = (const float*)d_in[3];
    const float* Wv  = (const float*)d_in[4];
    const float* Wo  = (const float*)d_in[5];
    float* out = (float*)d_out;

    // ws (bf16 elems): Xb 4M | WqkvT 6M | WoT 4M | QK 5M | Vt 1M  ~= 42 MB
    u16* Xb    = (u16*)d_ws;
    u16* WqkvT = Xb + (size_t)4194304;
    u16* WoT   = WqkvT + (size_t)6291456;
    u16* QK    = WoT + (size_t)4194304;
    u16* Vt    = QK + (size_t)S_LEN * QKD;
    u16* Ctxb  = Xb;   // Xb dead after QKV GEMM

    cast_bf16<<<2048, 256, 0, stream>>>(X, Xb, 524288);
    transpose_all<<<dim3(64, 64, 4), 256, 0, stream>>>(Wq, Wk, Wv, Wo, WqkvT, WoT);

    gemm_bt<1><<<dim3(24, 16), 256, 0, stream>>>(Xb, WqkvT, QK, Vt, 2048, 3072, 2048);

    rope_qk<<<10240, 256, 0, stream>>>(QK, pos);

    attn_mfma<<<dim3(16, 32), 256, 0, stream>>>(QK, Vt, Ctxb);

    gemm_bt<0><<<dim3(16, 16), 256, 0, stream>>>(Ctxb, WoT, out, nullptr, 2048, 2048, 2048);
}

// Round 10
// 257.227 us; speedup vs baseline: 1.0193x; 1.0193x over previous
//
#include <hip/hip_runtime.h>
#include <hip/hip_bf16.h>
#include <math.h>

#define S_LEN 2048
#define HID   2048
#define NH    32
#define NKV   8
#define HD    64
#define QKD   2560   // QK buffer row stride: Q[0:2048] | K[2048:2560]
#define LOG2E 1.44269504f
#define L2THETA_32 0.591611505f   // log2(500000)/32

typedef unsigned short u16;
typedef __attribute__((ext_vector_type(8))) short short8;   // 8 bf16 (MFMA A/B frag)
typedef __attribute__((ext_vector_type(4))) float f32x4;    // MFMA C/D frag

__device__ __forceinline__ u16 f2bf(float x) {
    union { __hip_bfloat16 b; u16 u; } c; c.b = __float2bfloat16(x); return c.u;
}
__device__ __forceinline__ float bf2f(u16 u) {
    union { unsigned int i; float f; } c; c.i = ((unsigned int)u) << 16; return c.f;
}
__device__ __forceinline__ void async_copy16(void* lds, const void* g) {
    __builtin_amdgcn_global_load_lds((const __attribute__((address_space(1))) unsigned int*)g,
                                     (__attribute__((address_space(3))) unsigned int*)lds,
                                     16, 0, 0);
}

// ---------------------------------------------------------------------------
__global__ __launch_bounds__(256)
void cast_bf16(const float* __restrict__ in, u16* __restrict__ out, int n8) {
    int i = blockIdx.x * blockDim.x + threadIdx.x;
    if (i >= n8) return;
    const float4* p = (const float4*)(in + (size_t)i * 8);
    float4 a = p[0], b = p[1];
    short8 o;
    o[0] = f2bf(a.x); o[1] = f2bf(a.y); o[2] = f2bf(a.z); o[3] = f2bf(a.w);
    o[4] = f2bf(b.x); o[5] = f2bf(b.y); o[6] = f2bf(b.z); o[7] = f2bf(b.w);
    *(short8*)(out + (size_t)i * 8) = o;
}

// ---------------------------------------------------------------------------
// All four weight transposes in one dispatch. z selects the weight.
// ---------------------------------------------------------------------------
__global__ __launch_bounds__(256)
void transpose_all(const float* __restrict__ Wq, const float* __restrict__ Wk,
                   const float* __restrict__ Wv, const float* __restrict__ Wo,
                   u16* __restrict__ WqkvT, u16* __restrict__ WoT) {
    const float* W; u16* WT; int Nin, xT;
    switch (blockIdx.z) {
        case 0:  W = Wq; WT = WqkvT;                         Nin = 2048; xT = 64; break;
        case 1:  W = Wk; WT = WqkvT + (size_t)2048 * 2048;   Nin = 512;  xT = 16; break;
        case 2:  W = Wv; WT = WqkvT + (size_t)2560 * 2048;   Nin = 512;  xT = 16; break;
        default: W = Wo; WT = WoT;                           Nin = 2048; xT = 64; break;
    }
    if ((int)blockIdx.x >= xT) return;
    __shared__ float tile[32][33];
    const int tx = threadIdx.x & 31, ty = threadIdx.x >> 5;
    const int x = blockIdx.x * 32 + tx;
#pragma unroll
    for (int j = ty; j < 32; j += 8)
        tile[j][tx] = W[(size_t)(blockIdx.y * 32 + j) * Nin + x];
    __syncthreads();
    const int xo = blockIdx.y * 32 + tx;
#pragma unroll
    for (int j = ty; j < 32; j += 8)
        WT[(size_t)(blockIdx.x * 32 + j) * 2048 + xo] = f2bf(tile[tx][j]);
}

// ---------------------------------------------------------------------------
// Standalone RoPE over Q (hh 0..31) and K (hh 32..39). Q gets 0.125*log2e
// folded in (attention works in the log2 domain and calls exp2 directly).
// ---------------------------------------------------------------------------
__global__ __launch_bounds__(256)
void rope_qk(u16* __restrict__ QK, const int* __restrict__ pos) {
    int idx = blockIdx.x * blockDim.x + threadIdx.x;
    int d = idx & 31;
    int hh = (idx >> 5) % 40;
    int s = idx / (32 * 40);
    if (s >= S_LEN) return;
    float p = (float)pos[s];
    float inv_freq = exp2f(-(float)d * L2THETA_32);   // theta^(-d/32)
    float ang = p * inv_freq;
    float c = cosf(ang), sn = sinf(ang);
    float sc = (hh < 32) ? 0.125f * LOG2E : 1.0f;
    u16* b = QK + (size_t)s * QKD + hh * HD;
    float x0 = bf2f(b[d]), x1 = bf2f(b[d + 32]);
    b[d]      = f2bf((x0 * c - x1 * sn) * sc);
    b[d + 32] = f2bf((x1 * c + x0 * sn) * sc);
}

// ---------------------------------------------------------------------------
// bf16 GEMM (R9): 512 threads / 8 waves, 128x128 tile, BK=32, double-buffered
// LDS with prefetch-in-flight (vmcnt(2) acquire — 2 vm ops per stage at 512
// thr). Wave micro-tile 32x64 (2x4 accs, 8 MFMAs/iter): per-CU MFMA work per
// iteration unchanged vs R8, but 2 waves/SIMD overlap each other's serial
// phases (these grids run ~1 block/CU — TLP must come from within the block).
// MODE 0: fp32 C (stride N).
// MODE 1: QKV epilogue — cols <2560 -> bf16 QK (stride QKD); cols >=2560 ->
// V written TRANSPOSED to Vt[d][s].
// ---------------------------------------------------------------------------
template<int MODE>
__global__ __launch_bounds__(512)
void gemm_bt(const u16* __restrict__ A, const u16* __restrict__ Bt,
             void* __restrict__ Cv, u16* __restrict__ Vt, int M, int N, int K) {
    __shared__ __attribute__((aligned(16))) u16 As[2][4096];   // 2 x 8KB
    __shared__ __attribute__((aligned(16))) u16 Bs[2][4096];   // 2 x 8KB
    const int t = threadIdx.x;           // 0..511
    const int lane = t & 63;
    const int w = t >> 6;                // 0..7
    const int lm = lane & 15, quad = lane >> 4;
    const int row0 = blockIdx.y * 128, col0 = blockIdx.x * 128;
    const int wr = (w >> 1) * 32, wc = (w & 1) * 64;   // wave = 32 rows x 64 cols

    f32x4 acc[2][4];
#pragma unroll
    for (int i = 0; i < 2; ++i)
#pragma unroll
        for (int j = 0; j < 4; ++j) acc[i][j] = (f32x4){0.f, 0.f, 0.f, 0.f};

    const size_t strideB = (size_t)K * 2;
    const char* Ab = (const char*)(A + (size_t)row0 * K);
    const char* Bb = (const char*)(Bt + (size_t)col0 * K);

    // stage one 128x32 k-tile pair: 2 vm ops per thread (A, B); 512x16B = 8KB
    auto stage = [&](int k0, int buf) {
        const int f = t * 16;
        const int r = f >> 6, cb = f & 63;
        async_copy16((char*)As[buf] + f, Ab + (size_t)r * strideB + k0 * 2 + cb);
        async_copy16((char*)Bs[buf] + f, Bb + (size_t)r * strideB + k0 * 2 + cb);
    };

    const int nk = K >> 5;
    stage(0, 0);
    if (nk > 1) stage(32, 1);

    for (int kk = 0; kk < nk; ++kk) {
        const int cur = kk & 1;
        // acquire: tile kk resident; tile kk+1 (2 ops) may stay in flight
        if (kk + 1 < nk) { asm volatile("s_waitcnt vmcnt(2)\ns_barrier" ::: "memory"); }
        else             { asm volatile("s_waitcnt vmcnt(0)\ns_barrier" ::: "memory"); }

        short8 af[2], bfv[4];
#pragma unroll
        for (int i = 0; i < 2; ++i)
            af[i] = *(const short8*)((const char*)As[cur] + (wr + 16 * i + lm) * 64 + quad * 16);
#pragma unroll
        for (int j = 0; j < 4; ++j)
            bfv[j] = *(const short8*)((const char*)Bs[cur] + (wc + 16 * j + lm) * 64 + quad * 16);
#pragma unroll
        for (int i = 0; i < 2; ++i)
#pragma unroll
            for (int j = 0; j < 4; ++j)
                acc[i][j] = __builtin_amdgcn_mfma_f32_16x16x32_bf16(af[i], bfv[j], acc[i][j], 0, 0, 0);

        // release: frag reads drained -> safe to re-stage this buffer
        asm volatile("s_waitcnt lgkmcnt(0)\ns_barrier" ::: "memory");
        if (kk + 2 < nk) stage((kk + 2) * 32, cur);
    }

    // C/D layout: col = lane&15, row = quad*4 + reg  [m89-verified]
    const int cr = quad * 4;
#pragma unroll
    for (int i = 0; i < 2; ++i) {
        const int gr = row0 + wr + 16 * i + cr;
#pragma unroll
        for (int j = 0; j < 4; ++j) {
            const int gc = col0 + wc + 16 * j + lm;
            if (MODE == 0) {
#pragma unroll
                for (int rr = 0; rr < 4; ++rr)
                    ((float*)Cv)[(size_t)(gr + rr) * N + gc] = acc[i][j][rr];
            } else if (gc < 2560) {
#pragma unroll
                for (int rr = 0; rr < 4; ++rr)
                    ((u16*)Cv)[(size_t)(gr + rr) * QKD + gc] = f2bf(acc[i][j][rr]);
            } else {
                const int d = gc - 2560;
                ushort4 vv;
                vv.x = f2bf(acc[i][j][0]); vv.y = f2bf(acc[i][j][1]);
                vv.z = f2bf(acc[i][j][2]); vv.w = f2bf(acc[i][j][3]);
                *(ushort4*)(Vt + (size_t)d * S_LEN + gr) = vv;
            }
        }
    }
}

// ---------------------------------------------------------------------------
// MFMA flash attention, Q-tile 128 (unchanged from R7 — 58.9 us). grid=
// (16 qtiles, 32 heads), 256 thr / 4 waves; wave w owns TWO 16-row q-groups
// (independent MFMA chains, shared K/V frags). KV-64 double-buffered with
// prefetch-in-flight (vmcnt(4) acquire). Q staging LDS aliased by P buffer.
// Scores in log2 domain, fixed cap -16; row sums via ones-fragment MFMA.
// ---------------------------------------------------------------------------
__global__ __launch_bounds__(256)
void attn_mfma(const u16* __restrict__ QK, const u16* __restrict__ Vtg,
               u16* __restrict__ Ctx) {
    // union region: Q staging (2 slabs x 8192B) then P (128 x 144B = 18432B)
    __shared__ __attribute__((aligned(16))) u16 QPs[9216];       // 18432B
    __shared__ __attribute__((aligned(16))) u16 Ks[2][4096];     // 2 x 8KB
    __shared__ __attribute__((aligned(16))) u16 Vts[2][4096];    // 2 x 8KB

    const int t = threadIdx.x;
    const int lane = t & 63;
    const int w = t >> 6;
    const int lm = lane & 15, quad = lane >> 4;
    const int qt = (gridDim.x - 1) - blockIdx.x;   // longest first (LPT)
    const int h = blockIdx.y;
    const int kh = h >> 2;
    const int q0 = qt * 128;
    const int njt = 2 * qt + 2;                    // kv tiles of 64

    const char* Kb = (const char*)(QK + 2048 + kh * HD);
    const char* Vb = (const char*)(Vtg + (size_t)(kh * 64) * S_LEN);

    const int rr4 = t >> 2, cb4 = (t & 3) * 16;

    // stage Q: wave w stages rows [w*32, w*32+32) for both k-slabs (4 vm ops;
    // read-set == staged-set per wave -> per-wave vmcnt wait is sufficient)
    {
        const char* qb = (const char*)(QK + h * HD);
#pragma unroll
        for (int i = 0; i < 2; ++i)
#pragma unroll
            for (int j = 0; j < 2; ++j)
                async_copy16((char*)QPs + i * 8192 + w * 2048 + j * 1024 + lane * 16,
                             qb + (size_t)(q0 + w * 32 + j * 16 + (lane >> 2)) * (QKD * 2)
                                + i * 64 + (lane & 3) * 16);
    }

    auto stage_kv = [&](int jt_, int buf) {
        const int j0_ = jt_ * 64;
        const char* kp = Kb + (size_t)(j0_ + rr4) * (QKD * 2) + cb4;
        const char* vp = Vb + (size_t)rr4 * (S_LEN * 2) + j0_ * 2 + cb4;
        char* kl = (char*)Ks + buf * 8192 + t * 16;
        char* vl = (char*)Vts + buf * 8192 + t * 16;
        async_copy16(kl, kp);
        async_copy16(kl + 4096, kp + 64);
        async_copy16(vl, vp);
        async_copy16(vl + 4096, vp + 64);
    };

    stage_kv(0, 0);
    stage_kv(1, 1);   // njt >= 2 always

    // wait for this wave's Q (4 oldest of 12); KV prefetches stay in flight
    asm volatile("s_waitcnt vmcnt(8)" ::: "memory");

    // one-time Q fragment loads (B-operand: rows = q)
    const int ra = w * 32 + lm, rb = ra + 16;
    const short8 qa0 = *(const short8*)((const char*)QPs +        ra * 64 + quad * 16);
    const short8 qa1 = *(const short8*)((const char*)QPs + 8192 + ra * 64 + quad * 16);
    const short8 qb0 = *(const short8*)((const char*)QPs +        rb * 64 + quad * 16);
    const short8 qb1 = *(const short8*)((const char*)QPs + 8192 + rb * 64 + quad * 16);
    // drain Q reads before any wave can alias QPs with P writes
    asm volatile("s_waitcnt lgkmcnt(0)" ::: "memory");

    // constant ones A-frag: row m=0 (lanes with lm==0) = 1.0
    short8 onesf;
    {
        const short ob = (lm == 0) ? (short)0x3F80 : (short)0;
#pragma unroll
        for (int j = 0; j < 8; ++j) onesf[j] = ob;
    }

    f32x4 oa[4], ob_[4], la, lb;
#pragma unroll
    for (int dt = 0; dt < 4; ++dt) { oa[dt] = (f32x4){0.f,0.f,0.f,0.f}; ob_[dt] = (f32x4){0.f,0.f,0.f,0.f}; }
    la = (f32x4){0.f, 0.f, 0.f, 0.f};
    lb = (f32x4){0.f, 0.f, 0.f, 0.f};

    const int ql_a = ra, ql_b = rb;   // local q row of this lane per group

    for (int jt = 0; jt < njt; ++jt) {
        const int cur = jt & 1;
        if (jt + 1 < njt) { asm volatile("s_waitcnt vmcnt(4)\ns_barrier" ::: "memory"); }
        else              { asm volatile("s_waitcnt vmcnt(0)\ns_barrier" ::: "memory"); }

        const char* Kc = (const char*)Ks + cur * 8192;
        const char* Vc = (const char*)Vts + cur * 8192;

        // S^T = K Q^T for both q-groups (shared K frags), log2 domain, cap -16
        f32x4 sa[4], sb[4];
#pragma unroll
        for (int ct = 0; ct < 4; ++ct) {
            sa[ct] = (f32x4){-16.f, -16.f, -16.f, -16.f};
            sb[ct] = (f32x4){-16.f, -16.f, -16.f, -16.f};
        }
#pragma unroll
        for (int ct = 0; ct < 4; ++ct) {
            short8 kf0 = *(const short8*)(Kc + (ct * 16 + lm) * 64 + quad * 16);
            short8 kf1 = *(const short8*)(Kc + 4096 + (ct * 16 + lm) * 64 + quad * 16);
            sa[ct] = __builtin_amdgcn_mfma_f32_16x16x32_bf16(kf0, qa0, sa[ct], 0, 0, 0);
            sa[ct] = __builtin_amdgcn_mfma_f32_16x16x32_bf16(kf1, qa1, sa[ct], 0, 0, 0);
            sb[ct] = __builtin_amdgcn_mfma_f32_16x16x32_bf16(kf0, qb0, sb[ct], 0, 0, 0);
            sb[ct] = __builtin_amdgcn_mfma_f32_16x16x32_bf16(kf1, qb1, sb[ct], 0, 0, 0);
        }
        // causal mask on the two diagonal-overlapping tiles
        if (jt >= 2 * qt) {
            const int off = (jt - 2 * qt) * 64;
#pragma unroll
            for (int ct = 0; ct < 4; ++ct) {
                const int kvl = off + ct * 16 + quad * 4;
#pragma unroll
                for (int r = 0; r < 4; ++r) {
                    if (kvl + r > ql_a) sa[ct][r] = -1e30f;
                    if (kvl + r > ql_b) sb[ct][r] = -1e30f;
                }
            }
        }
        // p = exp2(s); pack 4 kv -> one b64 LDS write per ct per group
#pragma unroll
        for (int ct = 0; ct < 4; ++ct) {
            ushort4 pka, pkb;
            pka.x = f2bf(__builtin_amdgcn_exp2f(sa[ct][0]));
            pka.y = f2bf(__builtin_amdgcn_exp2f(sa[ct][1]));
            pka.z = f2bf(__builtin_amdgcn_exp2f(sa[ct][2]));
            pka.w = f2bf(__builtin_amdgcn_exp2f(sa[ct][3]));
            pkb.x = f2bf(__builtin_amdgcn_exp2f(sb[ct][0]));
            pkb.y = f2bf(__builtin_amdgcn_exp2f(sb[ct][1]));
            pkb.z = f2bf(__builtin_amdgcn_exp2f(sb[ct][2]));
            pkb.w = f2bf(__builtin_amdgcn_exp2f(sb[ct][3]));
            *(ushort4*)((char*)QPs + ra * 144 + ct * 32 + quad * 8) = pka;
            *(ushort4*)((char*)QPs + rb * 144 + ct * 32 + quad * 8) = pkb;
        }
        // P frags (wave-private rows, in-order LDS pipe)
        const short8 pa0 = *(const short8*)((const char*)QPs + ra * 144 +      quad * 16);
        const short8 pa1 = *(const short8*)((const char*)QPs + ra * 144 + 64 + quad * 16);
        const short8 pb0 = *(const short8*)((const char*)QPs + rb * 144 +      quad * 16);
        const short8 pb1 = *(const short8*)((const char*)QPs + rb * 144 + 64 + quad * 16);
        // O^T += V^T P^T for both groups (shared V frags); l += ones . P
#pragma unroll
        for (int dt = 0; dt < 4; ++dt) {
            short8 vf0 = *(const short8*)(Vc + (dt * 16 + lm) * 64 + quad * 16);
            short8 vf1 = *(const short8*)(Vc + 4096 + (dt * 16 + lm) * 64 + quad * 16);
            oa[dt]  = __builtin_amdgcn_mfma_f32_16x16x32_bf16(vf0, pa0, oa[dt], 0, 0, 0);
            oa[dt]  = __builtin_amdgcn_mfma_f32_16x16x32_bf16(vf1, pa1, oa[dt], 0, 0, 0);
            ob_[dt] = __builtin_amdgcn_mfma_f32_16x16x32_bf16(vf0, pb0, ob_[dt], 0, 0, 0);
            ob_[dt] = __builtin_amdgcn_mfma_f32_16x16x32_bf16(vf1, pb1, ob_[dt], 0, 0, 0);
        }
        la = __builtin_amdgcn_mfma_f32_16x16x32_bf16(onesf, pa0, la, 0, 0, 0);
        la = __builtin_amdgcn_mfma_f32_16x16x32_bf16(onesf, pa1, la, 0, 0, 0);
        lb = __builtin_amdgcn_mfma_f32_16x16x32_bf16(onesf, pb0, lb, 0, 0, 0);
        lb = __builtin_amdgcn_mfma_f32_16x16x32_bf16(onesf, pb1, lb, 0, 0, 0);

        // all waves done reading buf[cur] -> safe to prefetch jt+2 into it
        asm volatile("s_waitcnt lgkmcnt(0)\ns_barrier" ::: "memory");
        if (jt + 2 < njt) stage_kv(jt + 2, cur);
    }

    // l for q-row ra/rb lives in lane lm (quad 0), reg 0 -> broadcast
    const float inva = 1.f / __shfl(la[0], lm);
    const float invb = 1.f / __shfl(lb[0], lm);
    const int rowa = q0 + ra, rowb = q0 + rb;
#pragma unroll
    for (int dt = 0; dt < 4; ++dt) {
        ushort4 o;
        o.x = f2bf(oa[dt][0] * inva); o.y = f2bf(oa[dt][1] * inva);
        o.z = f2bf(oa[dt][2] * inva); o.w = f2bf(oa[dt][3] * inva);
        *(ushort4*)(Ctx + (size_t)rowa * HID + h * HD + dt * 16 + quad * 4) = o;
        ushort4 p;
        p.x = f2bf(ob_[dt][0] * invb); p.y = f2bf(ob_[dt][1] * invb);
        p.z = f2bf(ob_[dt][2] * invb); p.w = f2bf(ob_[dt][3] * invb);
        *(ushort4*)(Ctx + (size_t)rowb * HID + h * HD + dt * 16 + quad * 4) = p;
    }
}

// ---------------------------------------------------------------------------
extern "C" void kernel_launch(void* const* d_in, const int* in_sizes, int n_in,
                              void* d_out, int out_size, void* d_ws, size_t ws_size,
                              hipStream_t stream) {
    const float* X   = (const float*)d_in[0];
    const int*   pos = (const int*)d_in[1];
    const float* Wq  = (const float*)d_in[2];
    const float* Wk  = (const float*)d_in[3];
    const float* Wv  = (const float*)d_in[4];
    const float* Wo  = (const float*)d_in[5];
    float* out = (float*)d_out;

    // ws (bf16 elems): Xb 4M | WqkvT 6M | WoT 4M | QK 5M | Vt 1M  ~= 42 MB
    u16* Xb    = (u16*)d_ws;
    u16* WqkvT = Xb + (size_t)4194304;
    u16* WoT   = WqkvT + (size_t)6291456;
    u16* QK    = WoT + (size_t)4194304;
    u16* Vt    = QK + (size_t)S_LEN * QKD;
    u16* Ctxb  = Xb;   // Xb dead after QKV GEMM

    cast_bf16<<<2048, 256, 0, stream>>>(X, Xb, 524288);
    transpose_all<<<dim3(64, 64, 4), 256, 0, stream>>>(Wq, Wk, Wv, Wo, WqkvT, WoT);

    gemm_bt<1><<<dim3(24, 16), 512, 0, stream>>>(Xb, WqkvT, QK, Vt, 2048, 3072, 2048);

    rope_qk<<<10240, 256, 0, stream>>>(QK, pos);

    attn_mfma<<<dim3(16, 32), 256, 0, stream>>>(QK, Vt, Ctxb);

    gemm_bt<0><<<dim3(16, 16), 512, 0, stream>>>(Ctxb, WoT, out, nullptr, 2048, 2048, 2048);
}